// Round 2
// baseline (105.368 us; speedup 1.0000x reference)
//
#include <hip/hip_runtime.h>

#define NSLOTS 128   // accumulator slots (128 cache lines) to avoid atomic serialization

__global__ __launch_bounds__(256) void moe_main(
    const float* __restrict__ xg,
    const float* __restrict__ w_embed,   // [4][16]
    const float* __restrict__ b_embed,   // [16]
    const float* __restrict__ gate_w,    // [16][8]
    const float* __restrict__ expert_w,  // [8][16][16]
    const float* __restrict__ expert_b,  // [8][16]
    const float* __restrict__ resid_w,   // [16][16]
    const float* __restrict__ resid_b,   // [16]
    const float* __restrict__ comb_w,    // [16][2]
    const float* __restrict__ comb_b,    // [2]
    const float* __restrict__ proj_w,    // [16][4]
    const float* __restrict__ proj_b,    // [4]
    float* __restrict__ out,
    float* __restrict__ ws,
    int ntok)
{
    // folded tables: EPx[e] (4x4) + c_e (4)  => 20 floats/expert, 80B stride:
    // expert rows start at dword-bank (20*e)%32 = {0,20,8,28,16,4,24,12};
    // each float4 read spans a disjoint 4-bank quad per expert -> conflict-free gather
    __shared__ float EP[8][16][4];                 // expert_w[e] @ proj_w (staging)
    __shared__ float RP[16][4];                    // resid_w @ proj_w    (staging)
    __shared__ __align__(16) float tblE[8][20];    // [ EPx(16) | c_e(4) ]
    __shared__ __align__(16) float tblR[20];       // [ RPx(16) | c_r(4) ]
    __shared__ __align__(16) float tblC[12];       // [ CWx(8)  | c_c(2) pad(2) ]

    const int tid = threadIdx.x;

    // ---- fold stage 1: EP[e] = expert_w[e] @ proj_w ; RP = resid_w @ proj_w
    #pragma unroll
    for (int r = 0; r < 2; ++r) {
        int idx = tid + 256 * r;                 // 0..511
        int e = idx >> 6, rem = idx & 63, d = rem >> 2, j = rem & 3;
        float s = 0.0f;
        #pragma unroll
        for (int h = 0; h < 16; ++h)
            s = fmaf(expert_w[e * 256 + d * 16 + h], proj_w[h * 4 + j], s);
        EP[e][d][j] = s;
    }
    if (tid < 64) {
        int d = tid >> 2, j = tid & 3;
        float s = 0.0f;
        #pragma unroll
        for (int h = 0; h < 16; ++h)
            s = fmaf(resid_w[d * 16 + h], proj_w[h * 4 + j], s);
        RP[d][j] = s;
    }
    __syncthreads();

    // ---- fold stage 2: fold w_embed/b_embed through everything downstream of router
    if (tid < 128) {                              // EPx[e][i][j] = sum_d w_embed[i][d]*EP[e][d][j]
        int e = tid >> 4, i = (tid >> 2) & 3, j = tid & 3;
        float s = 0.0f;
        #pragma unroll
        for (int d = 0; d < 16; ++d) s = fmaf(w_embed[i * 16 + d], EP[e][d][j], s);
        tblE[e][i * 4 + j] = s;
    } else if (tid < 160) {                       // c_e[j] = b_embed@EP[e] + expert_b[e]@proj_w
        int q = tid - 128, e = q >> 2, j = q & 3;
        float s = 0.0f;
        #pragma unroll
        for (int d = 0; d < 16; ++d) s = fmaf(b_embed[d], EP[e][d][j], s);
        #pragma unroll
        for (int h = 0; h < 16; ++h) s = fmaf(expert_b[e * 16 + h], proj_w[h * 4 + j], s);
        tblE[e][16 + j] = s;
    } else if (tid < 176) {                       // RPx
        int q = tid - 160, i = q >> 2, j = q & 3;
        float s = 0.0f;
        #pragma unroll
        for (int d = 0; d < 16; ++d) s = fmaf(w_embed[i * 16 + d], RP[d][j], s);
        tblR[i * 4 + j] = s;
    } else if (tid < 180) {                       // c_r
        int j = tid - 176;
        float s = 0.0f;
        #pragma unroll
        for (int d = 0; d < 16; ++d) s = fmaf(b_embed[d], RP[d][j], s);
        #pragma unroll
        for (int h = 0; h < 16; ++h) s = fmaf(resid_b[h], proj_w[h * 4 + j], s);
        tblR[16 + j] = s;
    } else if (tid < 188) {                       // CWx[i][c] = sum_d w_embed[i][d]*comb_w[d][c]
        int q = tid - 180, i = q >> 1, c = q & 1;
        float s = 0.0f;
        #pragma unroll
        for (int d = 0; d < 16; ++d) s = fmaf(w_embed[i * 16 + d], comb_w[d * 2 + c], s);
        tblC[i * 2 + c] = s;
    } else if (tid < 190) {                       // c_c
        int c = tid - 188;
        float s = comb_b[c];
        #pragma unroll
        for (int d = 0; d < 16; ++d) s = fmaf(b_embed[d], comb_w[d * 2 + c], s);
        tblC[8 + c] = s;
    }
    __syncthreads();

    // uniform folded tables -> registers (read once, reused for both tokens)
    float rpx[16], cr[4], cwx[8], cc[2];
    #pragma unroll
    for (int i = 0; i < 16; ++i) rpx[i] = tblR[i];
    #pragma unroll
    for (int j = 0; j < 4; ++j) cr[j] = tblR[16 + j];
    #pragma unroll
    for (int i = 0; i < 8; ++i) cwx[i] = tblC[i];
    cc[0] = tblC[8]; cc[1] = tblC[9];

    float psum[8], pcnt[8];
    #pragma unroll
    for (int e = 0; e < 8; ++e) { psum[e] = 0.0f; pcnt[e] = 0.0f; }

    // ---- main: 2 tokens per thread, fully coalesced float4 I/O
    #pragma unroll
    for (int t = 0; t < 2; ++t) {
        int nid = blockIdx.x * 512 + t * 256 + tid;
        if (nid < ntok) {
            float4 xv = ((const float4*)xg)[nid];

            // h = x @ w_embed + b_embed   (reference order: fp32, ascending i)
            float h[16];
            #pragma unroll
            for (int k = 0; k < 16; ++k) {
                float s = xv.x * w_embed[k];
                s = fmaf(xv.y, w_embed[16 + k], s);
                s = fmaf(xv.z, w_embed[32 + k], s);
                s = fmaf(xv.w, w_embed[48 + k], s);
                h[k] = s + b_embed[k];
            }

            // gate logits = h @ gate_w (reference order, ascending k) — protects argmax.
            // argmax(softmax(l)) == argmax(l) (softmax monotone), so use logits directly.
            float lg[8];
            #pragma unroll
            for (int e = 0; e < 8; ++e) {
                float s = h[0] * gate_w[e];
                #pragma unroll
                for (int k = 1; k < 16; ++k) s = fmaf(h[k], gate_w[k * 8 + e], s);
                lg[e] = s;
            }
            // argmax (first-max semantics == jnp.argmax)
            float m = lg[0]; int sel = 0;
            #pragma unroll
            for (int e = 1; e < 8; ++e) { if (lg[e] > m) { m = lg[e]; sel = e; } }
            // softmax
            float p[8], S = 0.0f;
            #pragma unroll
            for (int e = 0; e < 8; ++e) { p[e] = __expf(lg[e] - m); S += p[e]; }
            float inv = 1.0f / S;                 // gate_sel = p[sel]/S = exp(0)/S = 1/S
            #pragma unroll
            for (int e = 0; e < 8; ++e) psum[e] = fmaf(p[e], inv, psum[e]);
            #pragma unroll
            for (int e = 0; e < 8; ++e) pcnt[e] += (sel == e) ? 1.0f : 0.0f;
            float gs = inv;

            // gather folded expert table (5x ds_read_b128, conflict-free across experts)
            const float4* tep = (const float4*)(&tblE[sel][0]);
            float te[20];
            #pragma unroll
            for (int q = 0; q < 5; ++q) {
                float4 v = tep[q];
                te[4 * q + 0] = v.x; te[4 * q + 1] = v.y;
                te[4 * q + 2] = v.z; te[4 * q + 3] = v.w;
            }

            float mo[4], rp[4];
            #pragma unroll
            for (int j = 0; j < 4; ++j) {
                float s = te[16 + j];             // moe path (pre gate/comb scale), proj folded
                s = fmaf(xv.x, te[j],      s);
                s = fmaf(xv.y, te[4 + j],  s);
                s = fmaf(xv.z, te[8 + j],  s);
                s = fmaf(xv.w, te[12 + j], s);
                mo[j] = s;
                float r = cr[j];                  // resid path, proj folded
                r = fmaf(xv.x, rpx[j],      r);
                r = fmaf(xv.y, rpx[4 + j],  r);
                r = fmaf(xv.z, rpx[8 + j],  r);
                r = fmaf(xv.w, rpx[12 + j], r);
                rp[j] = r;
            }

            // combine-weight softmax (2-way)
            float l0 = cc[0], l1 = cc[1];
            l0 = fmaf(xv.x, cwx[0], l0); l1 = fmaf(xv.x, cwx[1], l1);
            l0 = fmaf(xv.y, cwx[2], l0); l1 = fmaf(xv.y, cwx[3], l1);
            l0 = fmaf(xv.z, cwx[4], l0); l1 = fmaf(xv.z, cwx[5], l1);
            l0 = fmaf(xv.w, cwx[6], l0); l1 = fmaf(xv.w, cwx[7], l1);
            float cm = fmaxf(l0, l1);
            float t0 = __expf(l0 - cm), t1 = __expf(l1 - cm);
            float ci = 1.0f / (t0 + t1);
            float cw0 = t0 * ci, cw1 = t1 * ci;

            float a = gs * cw0;
            float4 ov;
            ov.x = fmaf(a, mo[0], fmaf(cw1, rp[0], proj_b[0]));
            ov.y = fmaf(a, mo[1], fmaf(cw1, rp[1], proj_b[1]));
            ov.z = fmaf(a, mo[2], fmaf(cw1, rp[2], proj_b[2]));
            ov.w = fmaf(a, mo[3], fmaf(cw1, rp[3], proj_b[3]));
            ((float4*)out)[nid] = ov;
        }
    }

    // ---- aux-loss wave reduction: HALVING butterfly (20 shfl total, not 96).
    // Step s: keep the half of the value-vector matching lane bit (via cndmask
    // select, NOT runtime index -> arrays stay in registers), shuffle the rest.
    // After 3 halving steps lane l holds its 8-lane-group sum for expert l&7;
    // 3 more cross-group xors give the full 64-lane total on every lane.
    {
        const int lane = tid & 63;
        const bool b0 = lane & 1, b1 = lane & 2, b2 = lane & 4;

        float s4[4], c4[4];
        #pragma unroll
        for (int e = 0; e < 4; ++e) {
            float ks = b0 ? psum[2*e+1] : psum[2*e];
            float gv = b0 ? psum[2*e]   : psum[2*e+1];
            s4[e] = ks + __shfl_xor(gv, 1);
            float kc = b0 ? pcnt[2*e+1] : pcnt[2*e];
            float gc = b0 ? pcnt[2*e]   : pcnt[2*e+1];
            c4[e] = kc + __shfl_xor(gc, 1);
        }
        float s2[2], c2[2];
        #pragma unroll
        for (int e = 0; e < 2; ++e) {
            float ks = b1 ? s4[2*e+1] : s4[2*e];
            float gv = b1 ? s4[2*e]   : s4[2*e+1];
            s2[e] = ks + __shfl_xor(gv, 2);
            float kc = b1 ? c4[2*e+1] : c4[2*e];
            float gc = b1 ? c4[2*e]   : c4[2*e+1];
            c2[e] = kc + __shfl_xor(gc, 2);
        }
        float stot, ctot;
        {
            float ks = b2 ? s2[1] : s2[0];
            float gv = b2 ? s2[0] : s2[1];
            stot = ks + __shfl_xor(gv, 4);
            float kc = b2 ? c2[1] : c2[0];
            float gc = b2 ? c2[0] : c2[1];
            ctot = kc + __shfl_xor(gc, 4);
        }
        stot += __shfl_xor(stot, 8);  ctot += __shfl_xor(ctot, 8);
        stot += __shfl_xor(stot, 16); ctot += __shfl_xor(ctot, 16);
        stot += __shfl_xor(stot, 32); ctot += __shfl_xor(ctot, 32);

        if (lane < 8) {               // lane == expert id; 2 atomic instrs, 8 lanes active
            int wave = (blockIdx.x * 256 + tid) >> 6;
            float* slot = ws + (size_t)(wave & (NSLOTS - 1)) * 16;
            atomicAdd(slot + lane, stot);
            atomicAdd(slot + 8 + lane, ctot);
        }
    }
}

__global__ __launch_bounds__(256) void moe_finalize(const float* __restrict__ ws,
                                                    float* __restrict__ aux_out,
                                                    int ntok)
{
    __shared__ float part[16][17];   // [slice][col], +1 pad for column reads
    __shared__ float red[16];
    const int t = threadIdx.x;       // 256 threads
    const int col = t & 15, slice = t >> 4;
    float s = 0.0f;
    #pragma unroll
    for (int q = 0; q < NSLOTS / 16; ++q)
        s += ws[(size_t)(slice * (NSLOTS / 16) + q) * 16 + col];
    part[slice][col] = s;
    __syncthreads();
    if (t < 16) {
        float v = 0.0f;
        #pragma unroll
        for (int i = 0; i < 16; ++i) v += part[i][t];
        red[t] = v;
    }
    __syncthreads();
    if (t == 0) {
        const float invN = 1.0f / (float)ntok;
        float aux = 0.0f;
        #pragma unroll
        for (int e = 0; e < 8; ++e)
            aux += (red[e] * invN) * (red[8 + e] * invN);
        aux_out[0] = 8.0f * aux;
    }
}

extern "C" void kernel_launch(void* const* d_in, const int* in_sizes, int n_in,
                              void* d_out, int out_size, void* d_ws, size_t ws_size,
                              hipStream_t stream) {
    const float* xg       = (const float*)d_in[0];
    const float* w_embed  = (const float*)d_in[1];
    const float* b_embed  = (const float*)d_in[2];
    const float* gate_w   = (const float*)d_in[3];
    const float* expert_w = (const float*)d_in[4];
    const float* expert_b = (const float*)d_in[5];
    const float* resid_w  = (const float*)d_in[6];
    const float* resid_b  = (const float*)d_in[7];
    const float* comb_w   = (const float*)d_in[8];
    const float* comb_b   = (const float*)d_in[9];
    const float* proj_w   = (const float*)d_in[10];
    const float* proj_b   = (const float*)d_in[11];
    float* out = (float*)d_out;
    float* ws  = (float*)d_ws;

    int ntok = in_sizes[0] / 4;                 // 1<<20
    int grid = (ntok + 511) / 512;              // 512 tokens per block (2/thread)

    hipMemsetAsync(d_ws, 0, (size_t)NSLOTS * 16 * sizeof(float), stream);
    moe_main<<<grid, 256, 0, stream>>>(xg, w_embed, b_embed, gate_w, expert_w,
                                       expert_b, resid_w, resid_b, comb_w, comb_b,
                                       proj_w, proj_b, out, ws, ntok);
    moe_finalize<<<1, 256, 0, stream>>>(ws, out + (size_t)ntok * 4, ntok);
}